// Round 4
// baseline (3063.672 us; speedup 1.0000x reference)
//
#include <hip/hip_runtime.h>
#include <hip/hip_bf16.h>
#include <stdint.h>
#include <stddef.h>

#define NW    4096
#define LSEQ  24
#define HDIM  512
#define DWG   300
#define DCC   128
#define VCC   100
#define G4H   2048
#define CATD  812
#define HIDD  512
#define NOUT  5
#define NBLK  128   // LSTM blocks (32 rows each, no cross-block deps)
#define RB    32

typedef __bf16 bf16x8 __attribute__((ext_vector_type(8)));
typedef float  f32x16 __attribute__((ext_vector_type(16)));

__device__ __forceinline__ float frcp(float x) { return __builtin_amdgcn_rcpf(x); }
__device__ __forceinline__ float sigf(float x) { return frcp(1.0f + __expf(-x)); }
__device__ __forceinline__ float tanh_fast(float x) { return fmaf(2.0f, frcp(1.0f + __expf(-2.0f * x)), -1.0f); }

// ---- retile W_hh f32 [2048][512] -> bf16 k-panel-major: wt[((k>>4)*2048 + j)*16 + (k&15)] ----
__global__ void k_convert_wtile(const float* __restrict__ whh, __hip_bfloat16* __restrict__ wt) {
    const int tid = blockIdx.x * 256 + threadIdx.x;   // 65536 threads: (j, panel)
    const int j = tid >> 5, p = tid & 31;
    const float* src = whh + (size_t)j * HDIM + p * 16;
    union { bf16x8 v[2]; __hip_bfloat16 e[16]; } u;
#pragma unroll
    for (int i = 0; i < 4; ++i) {
        const float4 f = *reinterpret_cast<const float4*>(src + i * 4);
        u.e[i * 4 + 0] = __float2bfloat16(f.x);
        u.e[i * 4 + 1] = __float2bfloat16(f.y);
        u.e[i * 4 + 2] = __float2bfloat16(f.z);
        u.e[i * 4 + 3] = __float2bfloat16(f.w);
    }
    bf16x8* dst = reinterpret_cast<bf16x8*>(wt + (((size_t)p * G4H + j) << 4));
    dst[0] = u.v[0];
    dst[1] = u.v[1];
}

// ---- char_proj[c][j] = char_embed[c,:] @ W_ih[j,:] + b_ih[j] + b_hh[j]  (bf16 out) ----
__global__ void k_char_proj(const float* __restrict__ cemb, const float* __restrict__ wih,
                            const float* __restrict__ bih, const float* __restrict__ bhh,
                            __hip_bfloat16* __restrict__ cproj) {
    __shared__ float emb[DCC];
    const int c = blockIdx.x;
    if (threadIdx.x < DCC) emb[threadIdx.x] = cemb[c * DCC + threadIdx.x];
    __syncthreads();
    for (int j = threadIdx.x; j < G4H; j += blockDim.x) {
        const float* w = wih + (size_t)j * DCC;
        float acc = bih[j] + bhh[j];
#pragma unroll 4
        for (int k = 0; k < DCC; ++k) acc = fmaf(emb[k], w[k], acc);
        cproj[(size_t)c * G4H + j] = __float2bfloat16(acc);
    }
}

// ---- LSTM: block owns 32 rows for all 24 steps. 1024 thr = 16 waves (4/SIMD for latency
// hiding). Wave w owns hc-tile w (32 h-cols), all 4 gates via two 2-gate passes (i,g | f,o)
// to keep VGPR <= 128. h in swizzled 2x32KB LDS dbuf; c in regs; W streamed from L2 with
// 1-deep register prefetch. Only sync: one __syncthreads per step.
__global__ void __launch_bounds__(1024) k_lstm_block(
        const __hip_bfloat16* __restrict__ wt,     // [32 panels][2048][16] bf16
        const __hip_bfloat16* __restrict__ cproj,  // [100][2048] bf16
        const int* __restrict__ cidx,              // [NW][LSEQ]
        const int* __restrict__ clen,              // [NW]
        float* __restrict__ pchar) {               // [NBLK][512] partial col sums
    extern __shared__ char lds[];                  // 2 x 32KB h buffers, XOR-swizzled
    const int b = blockIdx.x;
    const int tid = threadIdx.x;
    const int w = tid >> 6, lane = tid & 63;
    const int l31 = lane & 31, lhi = lane >> 5;
    const int n0 = b * RB;

    {   // zero both h buffers (64 KB, 1024 threads x 4 x 16B)
        int4 z = {0, 0, 0, 0};
        int4* pz = (int4*)lds;
#pragma unroll
        for (int i = 0; i < 4; ++i) pz[i * 1024 + tid] = z;
    }

    // pack 16 char-lengths (rows rin(q)) into 4 regs, one byte each
    int lp[4];
#pragma unroll
    for (int j = 0; j < 4; ++j) {
        int v = 0;
#pragma unroll
        for (int k = 0; k < 4; ++k) {
            const int len = clen[n0 + j * 8 + (lhi << 2) + k];
            v |= (len & 0xff) << (k * 8);
        }
        lp[j] = v;
    }

    float cs[16];
#pragma unroll
    for (int q = 0; q < 16; ++q) cs[q] = 0.0f;

    const int xr   = (l31 & 15) << 4;
    const int colh = (w << 5) + l31;
    const char* wbase = (const char*)(wt + (((size_t)(w * 32 + l31)) << 4) + (lhi << 3));
    __syncthreads();

    for (int t = 0; t < LSEQ; ++t) {
        const int cur = t & 1;
        const char* rl = lds + (cur << 15) + (l31 << 10);   // A-frag rows
        const char* ro = lds + (cur << 15);                  // old-h region
        char* wl = lds + ((cur ^ 1) << 15);                  // write next buf

        float ig[16];

        // ---------- pass A: gates i (0) and g (2) ----------
        {
            f32x16 acc0 = {}, acc1 = {};
            if (t > 0) {
                bf16x8 nb0 = *reinterpret_cast<const bf16x8*>(wbase);
                bf16x8 nb1 = *reinterpret_cast<const bf16x8*>(wbase + 32768);
#pragma unroll
                for (int kp = 0; kp < 32; ++kp) {
                    const bf16x8 b0 = nb0, b1 = nb1;
                    if (kp < 31) {
                        nb0 = *reinterpret_cast<const bf16x8*>(wbase + (kp + 1) * 65536);
                        nb1 = *reinterpret_cast<const bf16x8*>(wbase + (kp + 1) * 65536 + 32768);
                    }
                    const bf16x8 a = *reinterpret_cast<const bf16x8*>(
                        rl + (((kp << 5) | (lhi << 4)) ^ xr));
                    acc0 = __builtin_amdgcn_mfma_f32_32x32x16_bf16(a, b0, acc0, 0, 0, 0);
                    acc1 = __builtin_amdgcn_mfma_f32_32x32x16_bf16(a, b1, acc1, 0, 0, 0);
                }
            }
#pragma unroll
            for (int q = 0; q < 16; ++q) {
                const int rin = (q & 3) + ((q >> 2) << 3) + (lhi << 2);
                const int ci = cidx[(n0 + rin) * LSEQ + t];
                const __hip_bfloat16* cp = cproj + ((size_t)ci << 11) + colh;
                const float gi = acc0[q] + __bfloat162float(cp[0]);
                const float gg = acc1[q] + __bfloat162float(cp[1024]);
                ig[q] = sigf(gi) * tanh_fast(gg);
            }
        }

        // ---------- pass B: gates f (1) and o (3), state update, h write ----------
        {
            f32x16 acc0 = {}, acc1 = {};
            if (t > 0) {
                bf16x8 nb0 = *reinterpret_cast<const bf16x8*>(wbase + 16384);
                bf16x8 nb1 = *reinterpret_cast<const bf16x8*>(wbase + 49152);
#pragma unroll
                for (int kp = 0; kp < 32; ++kp) {
                    const bf16x8 b0 = nb0, b1 = nb1;
                    if (kp < 31) {
                        nb0 = *reinterpret_cast<const bf16x8*>(wbase + (kp + 1) * 65536 + 16384);
                        nb1 = *reinterpret_cast<const bf16x8*>(wbase + (kp + 1) * 65536 + 49152);
                    }
                    const bf16x8 a = *reinterpret_cast<const bf16x8*>(
                        rl + (((kp << 5) | (lhi << 4)) ^ xr));
                    acc0 = __builtin_amdgcn_mfma_f32_32x32x16_bf16(a, b0, acc0, 0, 0, 0);
                    acc1 = __builtin_amdgcn_mfma_f32_32x32x16_bf16(a, b1, acc1, 0, 0, 0);
                }
            }
#pragma unroll
            for (int q = 0; q < 16; ++q) {
                const int rin = (q & 3) + ((q >> 2) << 3) + (lhi << 2);
                const int ci = cidx[(n0 + rin) * LSEQ + t];
                const __hip_bfloat16* cp = cproj + ((size_t)ci << 11) + colh;
                const float gf = acc0[q] + __bfloat162float(cp[512]);
                const float go = acc1[q] + __bfloat162float(cp[1536]);
                const float f_s = sigf(gf), o_s = sigf(go);
                const float cn = fmaf(f_s, cs[q], ig[q]);
                const int lenq = (lp[q >> 2] >> ((q & 3) * 8)) & 0xff;
                const bool valid = (t < lenq);
                cs[q] = valid ? cn : cs[q];
                const float hnew = o_s * tanh_fast(cn);
                const int sw = (rin << 10) + ((colh << 1) ^ ((rin & 15) << 4));
                const __hip_bfloat16 hold =
                    *reinterpret_cast<const __hip_bfloat16*>(ro + sw);
                *reinterpret_cast<__hip_bfloat16*>(wl + sw) =
                    valid ? __float2bfloat16(hnew) : hold;
            }
        }
        __syncthreads();
    }

    // block-local masked column partial sums; final h is in buffer 0 (t=23 wrote cur^1=0).
    // Values read were written by this same thread -> no barrier needed.
    float s = 0.0f;
#pragma unroll
    for (int q = 0; q < 16; ++q) {
        const int rin = (q & 3) + ((q >> 2) << 3) + (lhi << 2);
        const int lenq = (lp[q >> 2] >> ((q & 3) * 8)) & 0xff;
        const int sw = (rin << 10) + ((colh << 1) ^ ((rin & 15) << 4));
        const float hv = __bfloat162float(*reinterpret_cast<const __hip_bfloat16*>(lds + sw));
        s += (lenq >= 2) ? hv : 0.0f;
    }
    s += __shfl_xor(s, 32, 64);
    if (lhi == 0) pchar[b * HDIM + colh] = s;
}

// ---- glove gather column sums, 5x16 partial grid ----
__global__ void k_sum_glove(const float* __restrict__ gt, const int* __restrict__ widx,
                            float* __restrict__ pglove) {
    const int col = blockIdx.x * 64 + (threadIdx.x & 63);
    const int phase = threadIdx.x >> 6;
    const int nbase = blockIdx.y * 256;
    float s = 0.0f;
    if (col < DWG) {
        for (int n = nbase + phase; n < nbase + 256; n += 4) {
            s += gt[(size_t)widx[n] * DWG + col];
        }
    }
    __shared__ float red[256];
    red[threadIdx.x] = s;
    __syncthreads();
    if (phase == 0 && col < DWG) {
        pglove[blockIdx.y * DWG + col] =
            red[threadIdx.x] + red[threadIdx.x + 64] + red[threadIdx.x + 128] + red[threadIdx.x + 192];
    }
}

// ---- combine partials -> avg vector ----
__global__ void k_avg(const float* __restrict__ pglove, const float* __restrict__ pchar,
                      float* __restrict__ avg) {
    const int i = blockIdx.x * 256 + threadIdx.x;
    if (i >= CATD) return;
    float s = 0.0f;
    if (i < DWG) {
        for (int r = 0; r < 16; ++r) s += pglove[r * DWG + i];
    } else {
        const int c = i - DWG;
        for (int r = 0; r < NBLK; ++r) s += pchar[r * HDIM + c];
    }
    avg[i] = s * (1.0f / 4096.0f);
}

__global__ void k_fc1(const float* __restrict__ avg, const float* __restrict__ W,
                      const float* __restrict__ bias, float* __restrict__ h1) {
    const int wave = threadIdx.x >> 6, lane = threadIdx.x & 63;
    const int j = blockIdx.x * 8 + wave;
    const float* w = W + (size_t)j * CATD;
    float s = 0.0f;
    for (int k = lane; k < CATD; k += 64) s += avg[k] * w[k];
#pragma unroll
    for (int o = 32; o > 0; o >>= 1) s += __shfl_down(s, o, 64);
    if (lane == 0) h1[j] = sigf(s + bias[j]);
}

__global__ void k_fc2(const float* __restrict__ h1, const float* __restrict__ W,
                      const float* __restrict__ bias, float* __restrict__ out) {
    const int wave = threadIdx.x >> 6, lane = threadIdx.x & 63;
    const float* w = W + (size_t)wave * HIDD;
    float s = 0.0f;
    for (int k = lane; k < HIDD; k += 64) s += h1[k] * w[k];
#pragma unroll
    for (int o = 32; o > 0; o >>= 1) s += __shfl_down(s, o, 64);
    if (lane == 0) out[wave] = s + bias[wave];
}

extern "C" void kernel_launch(void* const* d_in, const int* in_sizes, int n_in,
                              void* d_out, int out_size, void* d_ws, size_t ws_size,
                              hipStream_t stream) {
    (void)in_sizes; (void)n_in; (void)out_size; (void)ws_size;
    const int*   widx  = (const int*)d_in[0];
    const int*   cidx  = (const int*)d_in[1];
    const int*   clen  = (const int*)d_in[2];
    const float* glove = (const float*)d_in[3];
    const float* cemb  = (const float*)d_in[4];
    const float* wih   = (const float*)d_in[5];
    const float* whh   = (const float*)d_in[6];
    const float* bih   = (const float*)d_in[7];
    const float* bhh   = (const float*)d_in[8];
    const float* fc1W  = (const float*)d_in[9];
    const float* fc1b  = (const float*)d_in[10];
    const float* fc2W  = (const float*)d_in[11];
    const float* fc2b  = (const float*)d_in[12];
    float* out = (float*)d_out;

    char* ws = (char*)d_ws;
    __hip_bfloat16* wt     = (__hip_bfloat16*)(ws);                         // 2 MB
    __hip_bfloat16* cproj  = (__hip_bfloat16*)(ws + (2u << 20));            // 400 KB
    float*          pchar  = (float*)(ws + (2u << 20) + (512u << 10));      // 256 KB
    float*          pglove = (float*)(ws + (2u << 20) + (768u << 10));      // 19.2 KB
    float*          avg    = (float*)(ws + (2u << 20) + (800u << 10));      // 3.2 KB
    float*          h1g    = (float*)(ws + (2u << 20) + (808u << 10));      // 2 KB

    k_convert_wtile<<<256, 256, 0, stream>>>(whh, wt);
    k_char_proj<<<VCC, 256, 0, stream>>>(cemb, wih, bih, bhh, cproj);
    k_lstm_block<<<NBLK, 1024, 65536, stream>>>(wt, cproj, cidx, clen, pchar);
    k_sum_glove<<<dim3(5, 16), 256, 0, stream>>>(glove, widx, pglove);
    k_avg<<<4, 256, 0, stream>>>(pglove, pchar, avg);
    k_fc1<<<64, 512, 0, stream>>>(avg, fc1W, fc1b, h1g);
    k_fc2<<<1, 320, 0, stream>>>(h1g, fc2W, fc2b, out);
}

// Round 5
// 2781.580 us; speedup vs baseline: 1.1014x; 1.1014x over previous
//
#include <hip/hip_runtime.h>
#include <hip/hip_bf16.h>
#include <stdint.h>
#include <stddef.h>

#define NW    4096
#define LSEQ  24
#define HDIM  512
#define DWG   300
#define DCC   128
#define VCC   100
#define G4H   2048
#define CATD  812
#define HIDD  512
#define NOUT  5
#define NBLK  128   // LSTM blocks (32 rows each, no cross-block deps)
#define RB    32

typedef __bf16 bf16x8 __attribute__((ext_vector_type(8)));
typedef float  f32x16 __attribute__((ext_vector_type(16)));

__device__ __forceinline__ float frcp(float x) { return __builtin_amdgcn_rcpf(x); }
__device__ __forceinline__ float sigf(float x) { return frcp(1.0f + __expf(-x)); }
__device__ __forceinline__ float tanh_fast(float x) { return fmaf(2.0f, frcp(1.0f + __expf(-2.0f * x)), -1.0f); }

// ---- retile W_hh f32 [2048][512] -> bf16 k-panel-major: wt[((k>>4)*2048 + j)*16 + (k&15)] ----
__global__ void k_convert_wtile(const float* __restrict__ whh, __hip_bfloat16* __restrict__ wt) {
    const int tid = blockIdx.x * 256 + threadIdx.x;   // 65536 threads: (j, panel)
    const int j = tid >> 5, p = tid & 31;
    const float* src = whh + (size_t)j * HDIM + p * 16;
    union { bf16x8 v[2]; __hip_bfloat16 e[16]; } u;
#pragma unroll
    for (int i = 0; i < 4; ++i) {
        const float4 f = *reinterpret_cast<const float4*>(src + i * 4);
        u.e[i * 4 + 0] = __float2bfloat16(f.x);
        u.e[i * 4 + 1] = __float2bfloat16(f.y);
        u.e[i * 4 + 2] = __float2bfloat16(f.z);
        u.e[i * 4 + 3] = __float2bfloat16(f.w);
    }
    bf16x8* dst = reinterpret_cast<bf16x8*>(wt + (((size_t)p * G4H + j) << 4));
    dst[0] = u.v[0];
    dst[1] = u.v[1];
}

// ---- char_proj[c][j] = char_embed[c,:] @ W_ih[j,:] + b_ih[j] + b_hh[j]  (bf16 out) ----
__global__ void k_char_proj(const float* __restrict__ cemb, const float* __restrict__ wih,
                            const float* __restrict__ bih, const float* __restrict__ bhh,
                            __hip_bfloat16* __restrict__ cproj) {
    __shared__ float emb[DCC];
    const int c = blockIdx.x;
    if (threadIdx.x < DCC) emb[threadIdx.x] = cemb[c * DCC + threadIdx.x];
    __syncthreads();
    for (int j = threadIdx.x; j < G4H; j += blockDim.x) {
        const float* w = wih + (size_t)j * DCC;
        float acc = bih[j] + bhh[j];
#pragma unroll 4
        for (int k = 0; k < DCC; ++k) acc = fmaf(emb[k], w[k], acc);
        cproj[(size_t)c * G4H + j] = __float2bfloat16(acc);
    }
}

// ---- LSTM: block owns 32 rows for all 24 steps. 1024 thr = 16 waves, pinned 4 waves/SIMD
// (launch_bounds(1024,4) -> VGPR cap 128; R4's (1024) defaulted to 64 VGPR and spilled).
// Wave w owns hc-tile w (32 h-cols), all 4 gates via two 2-gate passes (i,g | f,o).
// h in swizzled 2x32KB LDS dbuf; c in regs; W streamed from L2, full-unrolled K-loop.
__global__ void __launch_bounds__(1024, 4) k_lstm_block(
        const __hip_bfloat16* __restrict__ wt,     // [32 panels][2048][16] bf16
        const __hip_bfloat16* __restrict__ cproj,  // [100][2048] bf16
        const int* __restrict__ cidx,              // [NW][LSEQ]
        const int* __restrict__ clen,              // [NW]
        float* __restrict__ pchar) {               // [NBLK][512] partial col sums
    extern __shared__ char lds[];                  // 2 x 32KB h buffers, XOR-swizzled
    const int b = blockIdx.x;
    const int tid = threadIdx.x;
    const int w = tid >> 6, lane = tid & 63;
    const int l31 = lane & 31, lhi = lane >> 5;
    const int n0 = b * RB;

    {   // zero both h buffers (64 KB, 1024 threads x 4 x 16B)
        int4 z = {0, 0, 0, 0};
        int4* pz = (int4*)lds;
#pragma unroll
        for (int i = 0; i < 4; ++i) pz[i * 1024 + tid] = z;
    }

    // pack 16 char-lengths (rows rin(q)) into 4 regs, one byte each
    int lp[4];
#pragma unroll
    for (int j = 0; j < 4; ++j) {
        int v = 0;
#pragma unroll
        for (int k = 0; k < 4; ++k) {
            const int len = clen[n0 + j * 8 + (lhi << 2) + k];
            v |= (len & 0xff) << (k * 8);
        }
        lp[j] = v;
    }

    float cs[16];
#pragma unroll
    for (int q = 0; q < 16; ++q) cs[q] = 0.0f;

    const int xr   = (l31 & 15) << 4;
    const int colh = (w << 5) + l31;
    const char* wbase = (const char*)(wt + (((size_t)(w * 32 + l31)) << 4) + (lhi << 3));
    __syncthreads();

    for (int t = 0; t < LSEQ; ++t) {
        const int cur = t & 1;
        const char* rl = lds + (cur << 15) + (l31 << 10);   // A-frag rows
        const char* ro = lds + (cur << 15);                  // old-h region
        char* wl = lds + ((cur ^ 1) << 15);                  // write next buf

        float ig[16];

        // ---------- pass A: gates i (0) and g (2) ----------
        {
            f32x16 acc0 = {}, acc1 = {};
            if (t > 0) {
#pragma unroll
                for (int kp = 0; kp < 32; ++kp) {
                    const bf16x8 b0 = *reinterpret_cast<const bf16x8*>(wbase + kp * 65536);
                    const bf16x8 b1 = *reinterpret_cast<const bf16x8*>(wbase + kp * 65536 + 32768);
                    const bf16x8 a = *reinterpret_cast<const bf16x8*>(
                        rl + (((kp << 5) | (lhi << 4)) ^ xr));
                    acc0 = __builtin_amdgcn_mfma_f32_32x32x16_bf16(a, b0, acc0, 0, 0, 0);
                    acc1 = __builtin_amdgcn_mfma_f32_32x32x16_bf16(a, b1, acc1, 0, 0, 0);
                }
            }
#pragma unroll
            for (int q = 0; q < 16; ++q) {
                const int rin = (q & 3) + ((q >> 2) << 3) + (lhi << 2);
                const int ci = cidx[(n0 + rin) * LSEQ + t];
                const __hip_bfloat16* cp = cproj + ((size_t)ci << 11) + colh;
                const float gi = acc0[q] + __bfloat162float(cp[0]);
                const float gg = acc1[q] + __bfloat162float(cp[1024]);
                ig[q] = sigf(gi) * tanh_fast(gg);
            }
        }

        // ---------- pass B: gates f (1) and o (3), state update, h write ----------
        {
            f32x16 acc0 = {}, acc1 = {};
            if (t > 0) {
#pragma unroll
                for (int kp = 0; kp < 32; ++kp) {
                    const bf16x8 b0 = *reinterpret_cast<const bf16x8*>(wbase + kp * 65536 + 16384);
                    const bf16x8 b1 = *reinterpret_cast<const bf16x8*>(wbase + kp * 65536 + 49152);
                    const bf16x8 a = *reinterpret_cast<const bf16x8*>(
                        rl + (((kp << 5) | (lhi << 4)) ^ xr));
                    acc0 = __builtin_amdgcn_mfma_f32_32x32x16_bf16(a, b0, acc0, 0, 0, 0);
                    acc1 = __builtin_amdgcn_mfma_f32_32x32x16_bf16(a, b1, acc1, 0, 0, 0);
                }
            }
#pragma unroll
            for (int q = 0; q < 16; ++q) {
                const int rin = (q & 3) + ((q >> 2) << 3) + (lhi << 2);
                const int ci = cidx[(n0 + rin) * LSEQ + t];
                const __hip_bfloat16* cp = cproj + ((size_t)ci << 11) + colh;
                const float gf = acc0[q] + __bfloat162float(cp[512]);
                const float go = acc1[q] + __bfloat162float(cp[1536]);
                const float f_s = sigf(gf), o_s = sigf(go);
                const float cn = fmaf(f_s, cs[q], ig[q]);
                const int lenq = (lp[q >> 2] >> ((q & 3) * 8)) & 0xff;
                const bool valid = (t < lenq);
                cs[q] = valid ? cn : cs[q];
                const float hnew = o_s * tanh_fast(cn);
                const int sw = (rin << 10) + ((colh << 1) ^ ((rin & 15) << 4));
                const __hip_bfloat16 hold =
                    *reinterpret_cast<const __hip_bfloat16*>(ro + sw);
                *reinterpret_cast<__hip_bfloat16*>(wl + sw) =
                    valid ? __float2bfloat16(hnew) : hold;
            }
        }
        __syncthreads();
    }

    // block-local masked column partial sums; final h is in buffer 0 (t=23 wrote cur^1=0).
    // Values read were written by this same thread -> no barrier needed.
    float s = 0.0f;
#pragma unroll
    for (int q = 0; q < 16; ++q) {
        const int rin = (q & 3) + ((q >> 2) << 3) + (lhi << 2);
        const int lenq = (lp[q >> 2] >> ((q & 3) * 8)) & 0xff;
        const int sw = (rin << 10) + ((colh << 1) ^ ((rin & 15) << 4));
        const float hv = __bfloat162float(*reinterpret_cast<const __hip_bfloat16*>(lds + sw));
        s += (lenq >= 2) ? hv : 0.0f;
    }
    s += __shfl_xor(s, 32, 64);
    if (lhi == 0) pchar[b * HDIM + colh] = s;
}

// ---- glove gather column sums, 5x16 partial grid ----
__global__ void k_sum_glove(const float* __restrict__ gt, const int* __restrict__ widx,
                            float* __restrict__ pglove) {
    const int col = blockIdx.x * 64 + (threadIdx.x & 63);
    const int phase = threadIdx.x >> 6;
    const int nbase = blockIdx.y * 256;
    float s = 0.0f;
    if (col < DWG) {
        for (int n = nbase + phase; n < nbase + 256; n += 4) {
            s += gt[(size_t)widx[n] * DWG + col];
        }
    }
    __shared__ float red[256];
    red[threadIdx.x] = s;
    __syncthreads();
    if (phase == 0 && col < DWG) {
        pglove[blockIdx.y * DWG + col] =
            red[threadIdx.x] + red[threadIdx.x + 64] + red[threadIdx.x + 128] + red[threadIdx.x + 192];
    }
}

// ---- combine partials -> avg vector ----
__global__ void k_avg(const float* __restrict__ pglove, const float* __restrict__ pchar,
                      float* __restrict__ avg) {
    const int i = blockIdx.x * 256 + threadIdx.x;
    if (i >= CATD) return;
    float s = 0.0f;
    if (i < DWG) {
        for (int r = 0; r < 16; ++r) s += pglove[r * DWG + i];
    } else {
        const int c = i - DWG;
        for (int r = 0; r < NBLK; ++r) s += pchar[r * HDIM + c];
    }
    avg[i] = s * (1.0f / 4096.0f);
}

__global__ void k_fc1(const float* __restrict__ avg, const float* __restrict__ W,
                      const float* __restrict__ bias, float* __restrict__ h1) {
    const int wave = threadIdx.x >> 6, lane = threadIdx.x & 63;
    const int j = blockIdx.x * 8 + wave;
    const float* w = W + (size_t)j * CATD;
    float s = 0.0f;
    for (int k = lane; k < CATD; k += 64) s += avg[k] * w[k];
#pragma unroll
    for (int o = 32; o > 0; o >>= 1) s += __shfl_down(s, o, 64);
    if (lane == 0) h1[j] = sigf(s + bias[j]);
}

__global__ void k_fc2(const float* __restrict__ h1, const float* __restrict__ W,
                      const float* __restrict__ bias, float* __restrict__ out) {
    const int wave = threadIdx.x >> 6, lane = threadIdx.x & 63;
    const float* w = W + (size_t)wave * HIDD;
    float s = 0.0f;
    for (int k = lane; k < HIDD; k += 64) s += h1[k] * w[k];
#pragma unroll
    for (int o = 32; o > 0; o >>= 1) s += __shfl_down(s, o, 64);
    if (lane == 0) out[wave] = s + bias[wave];
}

extern "C" void kernel_launch(void* const* d_in, const int* in_sizes, int n_in,
                              void* d_out, int out_size, void* d_ws, size_t ws_size,
                              hipStream_t stream) {
    (void)in_sizes; (void)n_in; (void)out_size; (void)ws_size;
    const int*   widx  = (const int*)d_in[0];
    const int*   cidx  = (const int*)d_in[1];
    const int*   clen  = (const int*)d_in[2];
    const float* glove = (const float*)d_in[3];
    const float* cemb  = (const float*)d_in[4];
    const float* wih   = (const float*)d_in[5];
    const float* whh   = (const float*)d_in[6];
    const float* bih   = (const float*)d_in[7];
    const float* bhh   = (const float*)d_in[8];
    const float* fc1W  = (const float*)d_in[9];
    const float* fc1b  = (const float*)d_in[10];
    const float* fc2W  = (const float*)d_in[11];
    const float* fc2b  = (const float*)d_in[12];
    float* out = (float*)d_out;

    char* ws = (char*)d_ws;
    __hip_bfloat16* wt     = (__hip_bfloat16*)(ws);                         // 2 MB
    __hip_bfloat16* cproj  = (__hip_bfloat16*)(ws + (2u << 20));            // 400 KB
    float*          pchar  = (float*)(ws + (2u << 20) + (512u << 10));      // 256 KB
    float*          pglove = (float*)(ws + (2u << 20) + (768u << 10));      // 19.2 KB
    float*          avg    = (float*)(ws + (2u << 20) + (800u << 10));      // 3.2 KB
    float*          h1g    = (float*)(ws + (2u << 20) + (808u << 10));      // 2 KB

    k_convert_wtile<<<256, 256, 0, stream>>>(whh, wt);
    k_char_proj<<<VCC, 256, 0, stream>>>(cemb, wih, bih, bhh, cproj);
    k_lstm_block<<<NBLK, 1024, 65536, stream>>>(wt, cproj, cidx, clen, pchar);
    k_sum_glove<<<dim3(5, 16), 256, 0, stream>>>(glove, widx, pglove);
    k_avg<<<4, 256, 0, stream>>>(pglove, pchar, avg);
    k_fc1<<<64, 512, 0, stream>>>(avg, fc1W, fc1b, h1g);
    k_fc2<<<1, 320, 0, stream>>>(h1g, fc2W, fc2b, out);
}